// Round 5
// baseline (379.820 us; speedup 1.0000x reference)
//
#include <hip/hip_runtime.h>
#include <cstdint>
#include <cstddef>

typedef unsigned short u16;
typedef __bf16 bf16x8 __attribute__((ext_vector_type(8)));
typedef float f32x4 __attribute__((ext_vector_type(4)));
typedef unsigned int u32x4 __attribute__((ext_vector_type(4)));
typedef unsigned int u32x2 __attribute__((ext_vector_type(2)));
typedef u16 u16x4 __attribute__((ext_vector_type(4)));

typedef __attribute__((address_space(3))) void lds_void;
typedef __attribute__((address_space(1))) void glb_void;

constexpr float CEXP = 92.33248261689366f;   // 64 * log2(e): folded into Q

// ---------------- workspace layout (u16 element offsets) ----------------
constexpr size_t XSZ = 4096ull * 1024ull;   // one [4096,1024] bf16 array
constexpr size_t WSZ = 1024ull * 1024ull;   // one [1024,1024] bf16 array
constexpr size_t OFF_XQH = 0;
constexpr size_t OFF_XQL = OFF_XQH + XSZ;
constexpr size_t OFF_XKH = OFF_XQL + XSZ;
constexpr size_t OFF_XKL = OFF_XKH + XSZ;
constexpr size_t OFF_XVH = OFF_XKL + XSZ;
constexpr size_t OFF_XVL = OFF_XVH + XSZ;
constexpr size_t OFF_WQH = OFF_XVL + XSZ;
constexpr size_t OFF_WQL = OFF_WQH + WSZ;
constexpr size_t OFF_WKH = OFF_WQL + WSZ;
constexpr size_t OFF_WKL = OFF_WKH + WSZ;
constexpr size_t OFF_WVH = OFF_WKL + WSZ;
constexpr size_t OFF_WVL = OFF_WVH + WSZ;
constexpr size_t OFF_QH  = OFF_WVL + WSZ;   // [B,H,S,64]  (pre-scaled by CEXP)
constexpr size_t OFF_QL  = OFF_QH + XSZ;
constexpr size_t OFF_KH  = OFF_QL + XSZ;
constexpr size_t OFF_KL  = OFF_KH + XSZ;
constexpr size_t OFF_VT  = OFF_KL + XSZ;    // [B,H,64,S] (written directly by gemm)

// ---------------- helpers ----------------
__device__ __forceinline__ u16 f2b(float f) {           // fp32 -> bf16 RNE
  unsigned u = __builtin_bit_cast(unsigned, f);
  return (u16)((u + 0x7FFFu + ((u >> 16) & 1u)) >> 16);
}
__device__ __forceinline__ float b2f(u16 h) {
  return __builtin_bit_cast(float, ((unsigned)h) << 16);
}
__device__ __forceinline__ bf16x8 ld8(const u16* p) {   // 16B frag load
  return __builtin_bit_cast(bf16x8, *(const u32x4*)p);
}
__device__ __forceinline__ unsigned pk2(float a, float b) {  // pack 2 bf16 (RNE)
#if __has_builtin(__builtin_amdgcn_cvt_pk_bf16_f32)
  auto v = __builtin_amdgcn_cvt_pk_bf16_f32(a, b);
  return __builtin_bit_cast(unsigned, v);
#else
  return (unsigned)f2b(a) | ((unsigned)f2b(b) << 16);
#endif
}
__device__ __forceinline__ float ex2(float x) {         // raw v_exp_f32
#if __has_builtin(__builtin_amdgcn_exp2f)
  return __builtin_amdgcn_exp2f(x);
#else
  return exp2f(x);
#endif
}
__device__ __forceinline__ void glds16(const u16* g, u16* l) { // 16B global->LDS
  __builtin_amdgcn_global_load_lds((const glb_void*)g, (lds_void*)l, 16, 0, 0);
}
// swizzled LDS offset for a [rows][32 u16] tile: chunk = 8 u16 (16B)
__device__ __forceinline__ int swz32(int row, int cg) {
  return row * 32 + ((cg ^ ((row >> 1) & 3)) * 8);
}
// swizzled LDS offset for a [rows][64 u16] tile: chunk = 8 u16 (16B)
__device__ __forceinline__ int swz64(int row, int cg) {
  return row * 64 + ((cg ^ (row & 7)) * 8);
}

// ---------------- fp32 -> (hi,lo) bf16 elementwise, all 3 inputs ----------------
__global__ __launch_bounds__(256) void convert_x3(const float* __restrict__ q,
                                                  const float* __restrict__ k,
                                                  const float* __restrict__ v,
                                                  u16* __restrict__ ws) {
  int z = blockIdx.y;
  const float* in = (z == 0) ? q : (z == 1) ? k : v;
  u16* hi = ws + ((z == 0) ? OFF_XQH : (z == 1) ? OFF_XKH : OFF_XVH);
  u16* lo = ws + ((z == 0) ? OFF_XQL : (z == 1) ? OFF_XKL : OFF_XVL);
  size_t i = ((size_t)blockIdx.x * 256u + threadIdx.x) * 4u;
  float4 vv = *(const float4*)(in + i);
  float a[4] = {vv.x, vv.y, vv.z, vv.w};
  u16x4 hv, lv;
#pragma unroll
  for (int j = 0; j < 4; ++j) {
    u16 hb = f2b(a[j]);
    hv[j] = hb;
    lv[j] = f2b(a[j] - b2f(hb));
  }
  *(u16x4*)(hi + i) = hv;
  *(u16x4*)(lo + i) = lv;
}

// ---------------- W [K,N] fp32 -> Wt [N,K] (hi,lo) bf16, all 3 weights ----------
__global__ __launch_bounds__(256) void convert_w3(const float* __restrict__ Wq,
                                                  const float* __restrict__ Wk,
                                                  const float* __restrict__ Wv,
                                                  u16* __restrict__ ws) {
  int z = blockIdx.z;
  const float* W = (z == 0) ? Wq : (z == 1) ? Wk : Wv;
  u16* hiT = ws + ((z == 0) ? OFF_WQH : (z == 1) ? OFF_WKH : OFF_WVH);
  u16* loT = ws + ((z == 0) ? OFF_WQL : (z == 1) ? OFF_WKL : OFF_WVL);
  __shared__ float tile[32][33];
  int n0 = blockIdx.x * 32, k0 = blockIdx.y * 32;
  int t = threadIdx.x;
  int r = t >> 3, c0 = (t & 7) * 4;
  float4 v = *(const float4*)(W + (size_t)(k0 + r) * 1024 + n0 + c0);
  tile[r][c0] = v.x; tile[r][c0 + 1] = v.y; tile[r][c0 + 2] = v.z; tile[r][c0 + 3] = v.w;
  __syncthreads();
  u16x4 hv, lv;
#pragma unroll
  for (int j = 0; j < 4; ++j) {
    float x = tile[c0 + j][r];          // = W[k0+c0+j][n0+r]
    u16 hb = f2b(x);
    hv[j] = hb;
    lv[j] = f2b(x - b2f(hb));
  }
  size_t o = (size_t)(n0 + r) * 1024 + k0 + c0;
  *(u16x4*)(hiT + o) = hv;
  *(u16x4*)(loT + o) = lv;
}

// ---------------- QKV projection GEMM (combined split terms, global_load_lds) ----
// z=0: Q = hi*hi + lo*hi + hi*lo (hi/lo out, scaled by CEXP); z=1: K same;
// z=2: V hi*hi only, written DIRECTLY to Vt [B,H,64,S] (8B packed stores).
__global__ __launch_bounds__(256, 4) void gemm_qkv(u16* __restrict__ ws) {
  __shared__ u16 lah[128 * 32];
  __shared__ u16 lal[128 * 32];
  __shared__ u16 lbh[128 * 32];
  __shared__ u16 lbl[128 * 32];
  int z = blockIdx.z;
  const u16 *Ah, *Al, *Bh, *Bl; u16 *Oh, *Ol; bool split;
  if (z == 0)      { Ah = ws + OFF_XQH; Al = ws + OFF_XQL; Bh = ws + OFF_WQH; Bl = ws + OFF_WQL; Oh = ws + OFF_QH; Ol = ws + OFF_QL; split = true; }
  else if (z == 1) { Ah = ws + OFF_XKH; Al = ws + OFF_XKL; Bh = ws + OFF_WKH; Bl = ws + OFF_WKL; Oh = ws + OFF_KH; Ol = ws + OFF_KL; split = true; }
  else             { Ah = ws + OFF_XVH; Al = ws + OFF_XVH; Bh = ws + OFF_WVH; Bl = ws + OFF_WVH; Oh = ws + OFF_VT; Ol = nullptr;    split = false; }
  float oscale = (z == 0) ? CEXP : 1.0f;
  int m0 = blockIdx.y * 128, n0 = blockIdx.x * 128;
  int t = threadIdx.x, lane = t & 63, wave = t >> 6;
  int wm = (wave >> 1) * 64, wn = (wave & 1) * 64;
  int rl = lane >> 2, cgl = lane & 3;       // staging: 16 rows x 4 chunks per issue
  f32x4 acc[4][4] = {};
  // strength-reduced staging addresses (k0 added in-loop)
  size_t gA[2], gB[2]; int lb[2];
#pragma unroll
  for (int i = 0; i < 2; ++i) {
    int row = wave * 32 + i * 16 + rl;
    int cgg = cgl ^ ((row >> 1) & 3);
    gA[i] = (size_t)(m0 + row) * 1024 + cgg * 8;
    gB[i] = (size_t)(n0 + row) * 1024 + cgg * 8;
    lb[i] = (wave * 32 + i * 16) * 32;
  }
  for (int kb = 0; kb < 32; ++kb) {
    int k0 = kb * 32;
    __syncthreads();
#pragma unroll
    for (int i = 0; i < 2; ++i) {
      glds16(Ah + gA[i] + k0, &lah[lb[i]]);
      glds16(Bh + gB[i] + k0, &lbh[lb[i]]);
      if (split) {
        glds16(Al + gA[i] + k0, &lal[lb[i]]);
        glds16(Bl + gB[i] + k0, &lbl[lb[i]]);
      }
    }
    __syncthreads();
    int cg0 = lane >> 4;
    bf16x8 afh[4], afl[4], bfh[4], bfl[4];
#pragma unroll
    for (int i = 0; i < 4; ++i) {
      int ra = wm + i * 16 + (lane & 15);
      int rb = wn + i * 16 + (lane & 15);
      afh[i] = ld8(&lah[swz32(ra, cg0)]);
      bfh[i] = ld8(&lbh[swz32(rb, cg0)]);
      if (split) {
        afl[i] = ld8(&lal[swz32(ra, cg0)]);
        bfl[i] = ld8(&lbl[swz32(rb, cg0)]);
      }
    }
#pragma unroll
    for (int mt = 0; mt < 4; ++mt)
#pragma unroll
      for (int nt = 0; nt < 4; ++nt) {
        acc[mt][nt] = __builtin_amdgcn_mfma_f32_16x16x32_bf16(afh[mt], bfh[nt], acc[mt][nt], 0, 0, 0);
        if (split) {
          acc[mt][nt] = __builtin_amdgcn_mfma_f32_16x16x32_bf16(afl[mt], bfh[nt], acc[mt][nt], 0, 0, 0);
          acc[mt][nt] = __builtin_amdgcn_mfma_f32_16x16x32_bf16(afh[mt], bfl[nt], acc[mt][nt], 0, 0, 0);
        }
      }
  }
  // epilogue
  if (z == 2) {
    // Vt[((bb*16+hh)*64 + d) * 2048 + s]: r=0..3 are 4 consecutive s -> 8B store
#pragma unroll
    for (int mt = 0; mt < 4; ++mt)
#pragma unroll
      for (int nt = 0; nt < 4; ++nt) {
        int s_base = m0 + wm + mt * 16 + (lane >> 4) * 4;
        int gn = n0 + wn + nt * 16 + (lane & 15);
        int bb = s_base >> 11, s = s_base & 2047, hh = gn >> 6, d = gn & 63;
        u16x4 hv;
#pragma unroll
        for (int r = 0; r < 4; ++r) hv[r] = f2b(acc[mt][nt][r]);
        *(u16x4*)(Oh + ((size_t)((bb * 16 + hh) * 64 + d)) * 2048 + s) = hv;
      }
  } else {
#pragma unroll
    for (int mt = 0; mt < 4; ++mt)
#pragma unroll
      for (int nt = 0; nt < 4; ++nt)
#pragma unroll
        for (int r = 0; r < 4; ++r) {
          int gm = m0 + wm + mt * 16 + (lane >> 4) * 4 + r;
          int gn = n0 + wn + nt * 16 + (lane & 15);
          int bb = gm >> 11, s = gm & 2047, hh = gn >> 6, d = gn & 63;
          size_t oi = ((size_t)(bb * 16 + hh) * 2048 + s) * 64 + d;
          float val = acc[mt][nt][r] * oscale;
          u16 hb = f2b(val);
          Oh[oi] = hb;
          Ol[oi] = f2b(val - b2f(hb));
        }
  }
}

// ---------------- flash attention: 64 Q-rows/block, 64-key tiles -------------
// Single-buffer (4 blocks/CU, implicit wave-level overlap — R4's explicit dbuf
// regressed by dropping occupancy). QK^T operand-SWAPPED: sc = K_frag (A) x
// Q_frag (B) = S^T[key][qrow]. All LDS offsets hoisted; __launch_bounds__(256,4)
// raises the VGPR cap to 128 so the hoisted state stays resident (LDS already
// caps residency at 4 blocks/CU, so the higher VGPR use is free).
__global__ __launch_bounds__(256, 4) void attn(const u16* __restrict__ ws,
                                               float* __restrict__ out) {
  __shared__ u16 lkh[64 * 64];
  __shared__ u16 lkl[64 * 64];
  __shared__ u16 lvt[64 * 64];
  __shared__ u16 lp[4][16 * 64];     // per-wave P tile [qrow][key], swz64
  const u16* Qh = ws + OFF_QH; const u16* Ql = ws + OFF_QL;
  const u16* Kh = ws + OFF_KH; const u16* Kl = ws + OFF_KL;
  const u16* Vt = ws + OFF_VT;
  int b = blockIdx.z, h = blockIdx.y;
  int q0 = blockIdx.x * 64;
  int t = threadIdx.x, lane = t & 63, wave = t >> 6;
  int quad = lane >> 4, l15 = lane & 15;
  size_t hb = (size_t)(b * 16 + h) * (2048 * 64);
  bf16x8 onesf;                                  // ones B-frag for row-sum MFMA
#pragma unroll
  for (int j = 0; j < 8; ++j) onesf[j] = __builtin_bit_cast(__bf16, (u16)0x3F80);
  // Q fragments (B operand: lane holds qrow=lane&15, 8 consecutive d)
  int qrow = q0 + wave * 16 + l15;
  bf16x8 qfh[2], qfl[2];
#pragma unroll
  for (int ks = 0; ks < 2; ++ks) {
    size_t qo = hb + (size_t)qrow * 64 + ks * 32 + quad * 8;
    qfh[ks] = ld8(Qh + qo);
    qfl[ks] = ld8(Ql + qo);
  }
  float mi = -1e30f;                 // running max for qrow=l15 (St domain)
  f32x4 lsum = {};                   // row-sum accumulator (O domain)
  f32x4 o[4] = {};
  int rl = lane >> 3, cgl = lane & 7;            // staging: 8 rows x 8 chunks/issue

  // ---- hoisted loop-invariant addresses ----
  size_t aK[2], aV[2]; int lb[2];
#pragma unroll
  for (int i = 0; i < 2; ++i) {
    int row = wave * 16 + i * 8 + rl;            // tile-local row 0..63
    int cgg = cgl ^ (row & 7);
    aK[i] = hb + (size_t)row * 64 + cgg * 8;     // + kt*4096 in-loop
    aV[i] = hb + (size_t)row * 2048 + cgg * 8;   // + kt*64  in-loop
    lb[i] = (wave * 16 + i * 8) * 64;
  }
  int soF[2][4];                                  // K/V frag read offsets
#pragma unroll
  for (int ks = 0; ks < 2; ++ks)
#pragma unroll
    for (int nt = 0; nt < 4; ++nt)
      soF[ks][nt] = swz64(nt * 16 + l15, ks * 4 + quad);
  int soP[4];                                     // P store offsets
  {
    int r7 = l15 & 7;
#pragma unroll
    for (int nt = 0; nt < 4; ++nt) {
      int c = nt * 2 + (quad >> 1);
      soP[nt] = l15 * 64 + ((c ^ r7) * 8) + (quad & 1) * 4;
    }
  }
  int soPa[2];                                    // P frag read offsets
#pragma unroll
  for (int ks = 0; ks < 2; ++ks) soPa[ks] = swz64(l15, ks * 4 + quad);
  u16* lpw = &lp[wave][0];

  for (int kt = 0; kt < 32; ++kt) {
    __syncthreads();
#pragma unroll
    for (int i = 0; i < 2; ++i) {
      glds16(Kh + aK[i] + kt * 4096, &lkh[lb[i]]);
      glds16(Kl + aK[i] + kt * 4096, &lkl[lb[i]]);
      glds16(Vt + aV[i] + kt * 64,   &lvt[lb[i]]);
    }
    __syncthreads();
    // ---- QK^T (swapped): sc[nt] rows=keys nt*16+quad*4+r, col=qrow=l15 ----
    f32x4 sc[4] = {};
#pragma unroll
    for (int nt = 0; nt < 4; ++nt) {
#pragma unroll
      for (int ks = 0; ks < 2; ++ks) {
        bf16x8 kh_ = ld8(&lkh[soF[ks][nt]]);
        bf16x8 kl_ = ld8(&lkl[soF[ks][nt]]);
        sc[nt] = __builtin_amdgcn_mfma_f32_16x16x32_bf16(kh_, qfh[ks], sc[nt], 0, 0, 0);
        sc[nt] = __builtin_amdgcn_mfma_f32_16x16x32_bf16(kl_, qfh[ks], sc[nt], 0, 0, 0);
        sc[nt] = __builtin_amdgcn_mfma_f32_16x16x32_bf16(kh_, qfl[ks], sc[nt], 0, 0, 0);
      }
    }
    // ---- online softmax for qrow=l15: in-lane max over 16 keys + 2 shfl ----
    float mx = fmaxf(fmaxf(fmaxf(sc[0][0], sc[0][1]), fmaxf(sc[0][2], sc[0][3])),
                     fmaxf(fmaxf(sc[1][0], sc[1][1]), fmaxf(sc[1][2], sc[1][3])));
    float mx2 = fmaxf(fmaxf(fmaxf(sc[2][0], sc[2][1]), fmaxf(sc[2][2], sc[2][3])),
                      fmaxf(fmaxf(sc[3][0], sc[3][1]), fmaxf(sc[3][2], sc[3][3])));
    mx = fmaxf(mx, mx2);
    mx = fmaxf(mx, __shfl_xor(mx, 16));
    mx = fmaxf(mx, __shfl_xor(mx, 32));
    float mn = fmaxf(mi, mx);
    float alpha_s = ex2(mi - mn);
    mi = mn;
    // ---- P = exp2(sc - mn), packed ds_write_b64 into lp[qrow][key] ----
#pragma unroll
    for (int nt = 0; nt < 4; ++nt) {
      unsigned u01 = pk2(ex2(sc[nt][0] - mn), ex2(sc[nt][1] - mn));
      unsigned u23 = pk2(ex2(sc[nt][2] - mn), ex2(sc[nt][3] - mn));
      *(u32x2*)(&lpw[soP[nt]]) = u32x2{u01, u23};
    }
    // ---- rescale O domain only when some row-max actually updated ----
    if (__ballot(alpha_s != 1.0f)) {
      float av[4];
#pragma unroll
      for (int r = 0; r < 4; ++r) av[r] = __shfl(alpha_s, quad * 4 + r);
#pragma unroll
      for (int r = 0; r < 4; ++r) {
        lsum[r] *= av[r];
        o[0][r] *= av[r]; o[1][r] *= av[r]; o[2][r] *= av[r]; o[3][r] *= av[r];
      }
    }
    // wave-private LDS write->read: drain DS queue (in-order per wave)
    asm volatile("s_waitcnt lgkmcnt(0)" ::: "memory");
    // ---- P @ V (+ ones-B MFMA accumulates the row-sum l) ----
    bf16x8 pa[2];
#pragma unroll
    for (int ks = 0; ks < 2; ++ks) pa[ks] = ld8(&lpw[soPa[ks]]);
    lsum = __builtin_amdgcn_mfma_f32_16x16x32_bf16(pa[0], onesf, lsum, 0, 0, 0);
    lsum = __builtin_amdgcn_mfma_f32_16x16x32_bf16(pa[1], onesf, lsum, 0, 0, 0);
#pragma unroll
    for (int nt = 0; nt < 4; ++nt)
#pragma unroll
      for (int ks = 0; ks < 2; ++ks) {
        bf16x8 bv = ld8(&lvt[soF[ks][nt]]);
        o[nt] = __builtin_amdgcn_mfma_f32_16x16x32_bf16(pa[ks], bv, o[nt], 0, 0, 0);
      }
  }
  // epilogue: out[b, s, h*64+d]
  float inv[4];
#pragma unroll
  for (int r = 0; r < 4; ++r) inv[r] = 1.0f / lsum[r];
#pragma unroll
  for (int nt = 0; nt < 4; ++nt)
#pragma unroll
    for (int r = 0; r < 4; ++r) {
      int srow = q0 + wave * 16 + quad * 4 + r;
      int d = nt * 16 + l15;
      out[(size_t)(b * 2048 + srow) * 1024 + h * 64 + d] = o[nt][r] * inv[r];
    }
}

extern "C" void kernel_launch(void* const* d_in, const int* in_sizes, int n_in,
                              void* d_out, int out_size, void* d_ws, size_t ws_size,
                              hipStream_t stream) {
  const float* q  = (const float*)d_in[0];
  const float* k  = (const float*)d_in[1];
  const float* v  = (const float*)d_in[2];
  const float* Wq = (const float*)d_in[3];
  const float* Wk = (const float*)d_in[4];
  const float* Wv = (const float*)d_in[5];
  u16* ws = (u16*)d_ws;
  float* out = (float*)d_out;

  convert_x3<<<dim3(4096, 3), 256, 0, stream>>>(q, k, v, ws);
  convert_w3<<<dim3(32, 32, 3), 256, 0, stream>>>(Wq, Wk, Wv, ws);
  gemm_qkv<<<dim3(8, 32, 3), 256, 0, stream>>>(ws);
  attn<<<dim3(32, 16, 2), 256, 0, stream>>>(ws, out);
}

// Round 6
// 348.440 us; speedup vs baseline: 1.0901x; 1.0901x over previous
//
#include <hip/hip_runtime.h>
#include <cstdint>
#include <cstddef>

typedef unsigned short u16;
typedef __bf16 bf16x8 __attribute__((ext_vector_type(8)));
typedef float f32x4 __attribute__((ext_vector_type(4)));
typedef unsigned int u32x4 __attribute__((ext_vector_type(4)));
typedef unsigned int u32x2 __attribute__((ext_vector_type(2)));
typedef u16 u16x4 __attribute__((ext_vector_type(4)));

typedef __attribute__((address_space(3))) void lds_void;
typedef __attribute__((address_space(1))) void glb_void;

constexpr float CEXP = 92.33248261689366f;   // 64 * log2(e): folded into Q

// ---------------- workspace layout (u16 element offsets) ----------------
constexpr size_t XSZ = 4096ull * 1024ull;   // one [4096,1024] bf16 array
constexpr size_t WSZ = 1024ull * 1024ull;   // one [1024,1024] bf16 array
constexpr size_t OFF_XQH = 0;
constexpr size_t OFF_XQL = OFF_XQH + XSZ;
constexpr size_t OFF_XKH = OFF_XQL + XSZ;
constexpr size_t OFF_XKL = OFF_XKH + XSZ;
constexpr size_t OFF_XVH = OFF_XKL + XSZ;
constexpr size_t OFF_XVL = OFF_XVH + XSZ;
constexpr size_t OFF_WQH = OFF_XVL + XSZ;
constexpr size_t OFF_WQL = OFF_WQH + WSZ;
constexpr size_t OFF_WKH = OFF_WQL + WSZ;
constexpr size_t OFF_WKL = OFF_WKH + WSZ;
constexpr size_t OFF_WVH = OFF_WKL + WSZ;
constexpr size_t OFF_WVL = OFF_WVH + WSZ;
constexpr size_t OFF_QH  = OFF_WVL + WSZ;   // [B,H,S,64]  (pre-scaled by CEXP)
constexpr size_t OFF_QL  = OFF_QH + XSZ;
constexpr size_t OFF_KH  = OFF_QL + XSZ;
constexpr size_t OFF_KL  = OFF_KH + XSZ;
constexpr size_t OFF_VH  = OFF_KL + XSZ;    // [B,H,S,64]
constexpr size_t OFF_VT  = OFF_VH + XSZ;    // [B,H,64,S]

// ---------------- helpers ----------------
__device__ __forceinline__ u16 f2b(float f) {           // fp32 -> bf16 RNE
  unsigned u = __builtin_bit_cast(unsigned, f);
  return (u16)((u + 0x7FFFu + ((u >> 16) & 1u)) >> 16);
}
__device__ __forceinline__ float b2f(u16 h) {
  return __builtin_bit_cast(float, ((unsigned)h) << 16);
}
__device__ __forceinline__ bf16x8 ld8(const u16* p) {   // 16B frag load
  return __builtin_bit_cast(bf16x8, *(const u32x4*)p);
}
__device__ __forceinline__ unsigned pk2(float a, float b) {  // pack 2 bf16 (RNE)
#if __has_builtin(__builtin_amdgcn_cvt_pk_bf16_f32)
  auto v = __builtin_amdgcn_cvt_pk_bf16_f32(a, b);
  return __builtin_bit_cast(unsigned, v);
#else
  return (unsigned)f2b(a) | ((unsigned)f2b(b) << 16);
#endif
}
__device__ __forceinline__ void glds16(const u16* g, u16* l) { // 16B global->LDS
  __builtin_amdgcn_global_load_lds((const glb_void*)g, (lds_void*)l, 16, 0, 0);
}
// swizzled LDS offset for a [rows][32 u16] tile: chunk = 8 u16 (16B)
__device__ __forceinline__ int swz32(int row, int cg) {
  return row * 32 + ((cg ^ ((row >> 1) & 3)) * 8);
}
// swizzled LDS offset for a [rows][64 u16] tile: chunk = 8 u16 (16B)
__device__ __forceinline__ int swz64(int row, int cg) {
  return row * 64 + ((cg ^ (row & 7)) * 8);
}

// ---------------- fp32 -> (hi,lo) bf16 elementwise, all 3 inputs ----------------
__global__ __launch_bounds__(256) void convert_x3(const float* __restrict__ q,
                                                  const float* __restrict__ k,
                                                  const float* __restrict__ v,
                                                  u16* __restrict__ ws) {
  int z = blockIdx.y;
  const float* in = (z == 0) ? q : (z == 1) ? k : v;
  u16* hi = ws + ((z == 0) ? OFF_XQH : (z == 1) ? OFF_XKH : OFF_XVH);
  u16* lo = ws + ((z == 0) ? OFF_XQL : (z == 1) ? OFF_XKL : OFF_XVL);
  size_t i = ((size_t)blockIdx.x * 256u + threadIdx.x) * 4u;
  float4 vv = *(const float4*)(in + i);
  float a[4] = {vv.x, vv.y, vv.z, vv.w};
  u16x4 hv, lv;
#pragma unroll
  for (int j = 0; j < 4; ++j) {
    u16 hb = f2b(a[j]);
    hv[j] = hb;
    lv[j] = f2b(a[j] - b2f(hb));
  }
  *(u16x4*)(hi + i) = hv;
  *(u16x4*)(lo + i) = lv;
}

// ---------------- W [K,N] fp32 -> Wt [N,K] (hi,lo) bf16, all 3 weights ----------
__global__ __launch_bounds__(256) void convert_w3(const float* __restrict__ Wq,
                                                  const float* __restrict__ Wk,
                                                  const float* __restrict__ Wv,
                                                  u16* __restrict__ ws) {
  int z = blockIdx.z;
  const float* W = (z == 0) ? Wq : (z == 1) ? Wk : Wv;
  u16* hiT = ws + ((z == 0) ? OFF_WQH : (z == 1) ? OFF_WKH : OFF_WVH);
  u16* loT = ws + ((z == 0) ? OFF_WQL : (z == 1) ? OFF_WKL : OFF_WVL);
  __shared__ float tile[32][33];
  int n0 = blockIdx.x * 32, k0 = blockIdx.y * 32;
  int t = threadIdx.x;
  int r = t >> 3, c0 = (t & 7) * 4;
  float4 v = *(const float4*)(W + (size_t)(k0 + r) * 1024 + n0 + c0);
  tile[r][c0] = v.x; tile[r][c0 + 1] = v.y; tile[r][c0 + 2] = v.z; tile[r][c0 + 3] = v.w;
  __syncthreads();
  u16x4 hv, lv;
#pragma unroll
  for (int j = 0; j < 4; ++j) {
    float x = tile[c0 + j][r];          // = W[k0+c0+j][n0+r]
    u16 hb = f2b(x);
    hv[j] = hb;
    lv[j] = f2b(x - b2f(hb));
  }
  size_t o = (size_t)(n0 + r) * 1024 + k0 + c0;
  *(u16x4*)(hiT + o) = hv;
  *(u16x4*)(loT + o) = lv;
}

// ---------------- QKV projection GEMM (combined split terms, global_load_lds) ----
// 1D grid of 768 blocks with XCD swizzle: assuming round-robin dispatch
// (xcd = id % 8), all 8 n-blocks of one (z, m) tile-row land on the SAME XCD,
// so the shared 512 KB A-tile is fetched from HBM once and served from that
// XCD's L2 (R5 counters: A over-fetch ~8x without this).
// Epilogue stages the C tile through LDS (XOR-chunk swizzle) and stores
// 128B-aligned dwordx4 runs — full HBM sectors (R5: 254 MB written vs 40 ideal).
// z=0: Q = hi*hi+lo*hi+hi*lo (hi/lo out, scaled CEXP); z=1: K same; z=2: V hi*hi.
__global__ __launch_bounds__(256) void gemm_qkv(u16* __restrict__ ws) {
  __shared__ u16 smem[4][128 * 32];   // 32 KB staging; reused as 128x128 C buffer
  u16* lah = smem[0]; u16* lal = smem[1];
  u16* lbh = smem[2]; u16* lbl = smem[3];
  u16* cbuf = &smem[0][0];            // flat 16384 u16 epilogue view

  int id = blockIdx.x;
  int xcd = id & 7, seq = id >> 3;          // 96 blocks per XCD
  int pair = xcd * 12 + (seq >> 3);         // (z, m) tile-row, 0..95
  int tile_n = seq & 7;
  int z = pair >> 5;                        // pair / 32
  int tile_m = pair & 31;

  const u16 *Ah, *Al, *Bh, *Bl; u16 *Oh, *Ol; bool split;
  if (z == 0)      { Ah = ws + OFF_XQH; Al = ws + OFF_XQL; Bh = ws + OFF_WQH; Bl = ws + OFF_WQL; Oh = ws + OFF_QH; Ol = ws + OFF_QL; split = true; }
  else if (z == 1) { Ah = ws + OFF_XKH; Al = ws + OFF_XKL; Bh = ws + OFF_WKH; Bl = ws + OFF_WKL; Oh = ws + OFF_KH; Ol = ws + OFF_KL; split = true; }
  else             { Ah = ws + OFF_XVH; Al = ws + OFF_XVH; Bh = ws + OFF_WVH; Bl = ws + OFF_WVH; Oh = ws + OFF_VH; Ol = nullptr;    split = false; }
  float oscale = (z == 0) ? CEXP : 1.0f;
  int m0 = tile_m * 128, n0 = tile_n * 128;
  int t = threadIdx.x, lane = t & 63, wave = t >> 6;
  int wm = (wave >> 1) * 64, wn = (wave & 1) * 64;
  int rl = lane >> 2, cgl = lane & 3;       // staging: 16 rows x 4 chunks per issue
  f32x4 acc[4][4] = {};
  for (int kb = 0; kb < 32; ++kb) {
    int k0 = kb * 32;
    __syncthreads();
#pragma unroll
    for (int i = 0; i < 2; ++i) {
      int row = wave * 32 + i * 16 + rl;            // tile-local row 0..127
      int cgg = cgl ^ ((row >> 1) & 3);
      size_t ga = (size_t)(m0 + row) * 1024 + k0 + cgg * 8;
      size_t gb = (size_t)(n0 + row) * 1024 + k0 + cgg * 8;
      int lbase = (wave * 32 + i * 16) * 32;        // wave-uniform
      glds16(Ah + ga, &lah[lbase]);
      glds16(Bh + gb, &lbh[lbase]);
      if (split) {
        glds16(Al + ga, &lal[lbase]);
        glds16(Bl + gb, &lbl[lbase]);
      }
    }
    __syncthreads();
    int cg0 = lane >> 4;
    bf16x8 afh[4], afl[4], bfh[4], bfl[4];
#pragma unroll
    for (int i = 0; i < 4; ++i) {
      int ra = wm + i * 16 + (lane & 15);
      int rb = wn + i * 16 + (lane & 15);
      afh[i] = ld8(&lah[swz32(ra, cg0)]);
      bfh[i] = ld8(&lbh[swz32(rb, cg0)]);
      if (split) {
        afl[i] = ld8(&lal[swz32(ra, cg0)]);
        bfl[i] = ld8(&lbl[swz32(rb, cg0)]);
      }
    }
#pragma unroll
    for (int mt = 0; mt < 4; ++mt)
#pragma unroll
      for (int nt = 0; nt < 4; ++nt) {
        acc[mt][nt] = __builtin_amdgcn_mfma_f32_16x16x32_bf16(afh[mt], bfh[nt], acc[mt][nt], 0, 0, 0);
        if (split) {
          acc[mt][nt] = __builtin_amdgcn_mfma_f32_16x16x32_bf16(afl[mt], bfh[nt], acc[mt][nt], 0, 0, 0);
          acc[mt][nt] = __builtin_amdgcn_mfma_f32_16x16x32_bf16(afh[mt], bfl[nt], acc[mt][nt], 0, 0, 0);
        }
      }
  }
  // ---- LDS-staged coalesced epilogue ----
  // cbuf layout: [row 0..127][16 chunks of 8 u16], chunk XOR-swizzled by row&15.
  auto epi_round = [&](u16* dst, bool lo_round) {
#pragma unroll
    for (int mt = 0; mt < 4; ++mt)
#pragma unroll
      for (int nt = 0; nt < 4; ++nt)
#pragma unroll
        for (int r = 0; r < 4; ++r) {
          int row = wm + mt * 16 + (lane >> 4) * 4 + r;
          int col = wn + nt * 16 + (lane & 15);
          float v = acc[mt][nt][r] * oscale;
          u16 hb = f2b(v);
          u16 val = lo_round ? f2b(v - b2f(hb)) : hb;
          cbuf[row * 128 + (((col >> 3) ^ (row & 15)) * 8) + (col & 7)] = val;
        }
    __syncthreads();
    // each thread stores one 128B run: (row, head-half) -> out[.., s, d0..63]
    int orow = t >> 1, half = t & 1;
    int gm = m0 + orow, bb = gm >> 11, s = gm & 2047;
    int hh = (n0 >> 6) + half;
    u16* gp = dst + ((size_t)(bb * 16 + hh) * 2048 + s) * 64;
#pragma unroll
    for (int i = 0; i < 8; ++i) {
      int phys = (half * 8 + i) ^ (orow & 15);
      *(u32x4*)(gp + i * 8) = *(const u32x4*)(&cbuf[orow * 128 + phys * 8]);
    }
  };
  __syncthreads();                 // staging buffers free to overwrite
  epi_round(Oh, false);
  if (Ol) {
    __syncthreads();
    epi_round(Ol, true);
  }
}

// ---------------- V [B,H,S,64] -> Vt [B,H,64,S] ----------------
__global__ __launch_bounds__(256) void transpose_v(const u16* __restrict__ vh,
                                                   u16* __restrict__ vt) {
  __shared__ u16 tile[64][72];
  int bh = blockIdx.y;                 // b*16+h
  int s0 = blockIdx.x * 64;
  int t = threadIdx.x;
  for (int c = t; c < 512; c += 256) {
    int row = c >> 3, off = (c & 7) * 8;
    *(u32x4*)(&tile[row][off]) = *(const u32x4*)(vh + ((size_t)bh * 2048 + s0 + row) * 64 + off);
  }
  __syncthreads();
  int d = t >> 2, i0 = (t & 3) * 16;
  u16 vals[16];
#pragma unroll
  for (int i = 0; i < 16; ++i) vals[i] = tile[i0 + i][d];
  u16* outp = vt + ((size_t)bh * 64 + d) * 2048 + s0 + i0;
  *(u32x4*)(outp)     = *(u32x4*)(&vals[0]);
  *(u32x4*)(outp + 8) = *(u32x4*)(&vals[8]);
}

// ---------------- flash attention: 64 Q-rows/block, 64-key tiles -------------
// R3-measured version (125 us): single-buffer 2-barrier K-loop, QK^T operand-
// SWAPPED (sc = K_frag x Q_frag = S^T[key][qrow]) so each lane holds 4
// consecutive keys of ONE qrow: cheap max-reduce (2 shfl) + packed P stores.
__global__ __launch_bounds__(256) void attn(const u16* __restrict__ ws,
                                            float* __restrict__ out) {
  __shared__ u16 lkh[64 * 64];
  __shared__ u16 lkl[64 * 64];
  __shared__ u16 lvt[64 * 64];
  __shared__ u16 lp[4][16 * 64];     // per-wave P tile [qrow][key], swz64
  const u16* Qh = ws + OFF_QH; const u16* Ql = ws + OFF_QL;
  const u16* Kh = ws + OFF_KH; const u16* Kl = ws + OFF_KL;
  const u16* Vt = ws + OFF_VT;
  int b = blockIdx.z, h = blockIdx.y;
  int q0 = blockIdx.x * 64;
  int t = threadIdx.x, lane = t & 63, wave = t >> 6;
  int quad = lane >> 4, l15 = lane & 15;
  size_t hb = (size_t)(b * 16 + h) * (2048 * 64);
  bf16x8 onesf;                                  // ones B-frag for row-sum MFMA
#pragma unroll
  for (int j = 0; j < 8; ++j) onesf[j] = __builtin_bit_cast(__bf16, (u16)0x3F80);
  // Q fragments (B operand: lane holds qrow=lane&15, 8 consecutive d)
  int qrow = q0 + wave * 16 + l15;
  bf16x8 qfh[2], qfl[2];
#pragma unroll
  for (int ks = 0; ks < 2; ++ks) {
    size_t qo = hb + (size_t)qrow * 64 + ks * 32 + quad * 8;
    qfh[ks] = ld8(Qh + qo);
    qfl[ks] = ld8(Ql + qo);
  }
  float mi = -1e30f;                 // running max for qrow=l15 (St domain)
  f32x4 lsum = {};                   // row-sum accumulator (O domain)
  f32x4 o[4] = {};
  int rl = lane >> 3, cgl = lane & 7;            // staging: 8 rows x 8 chunks/issue

  for (int kt = 0; kt < 32; ++kt) {
    __syncthreads();
#pragma unroll
    for (int i = 0; i < 2; ++i) {
      int row = wave * 16 + i * 8 + rl;          // tile-local row 0..63
      int cgg = cgl ^ (row & 7);
      int lbase = (wave * 16 + i * 8) * 64;      // wave-uniform
      size_t gk = hb + (size_t)(kt * 64 + row) * 64 + cgg * 8;   // K: [key][d]
      glds16(Kh + gk, &lkh[lbase]);
      glds16(Kl + gk, &lkl[lbase]);
      size_t gv = hb + (size_t)row * 2048 + kt * 64 + cgg * 8;   // Vt: [d][key]
      glds16(Vt + gv, &lvt[lbase]);
    }
    __syncthreads();
    // ---- QK^T (swapped): sc[nt] = S^T block, rows=keys nt*16+quad*4+r, col=qrow=l15
    f32x4 sc[4] = {};
#pragma unroll
    for (int nt = 0; nt < 4; ++nt) {
#pragma unroll
      for (int ks = 0; ks < 2; ++ks) {
        int so = swz64(nt * 16 + l15, ks * 4 + quad);
        bf16x8 kh_ = ld8(&lkh[so]);
        bf16x8 kl_ = ld8(&lkl[so]);
        sc[nt] = __builtin_amdgcn_mfma_f32_16x16x32_bf16(kh_, qfh[ks], sc[nt], 0, 0, 0);
        sc[nt] = __builtin_amdgcn_mfma_f32_16x16x32_bf16(kl_, qfh[ks], sc[nt], 0, 0, 0);
        sc[nt] = __builtin_amdgcn_mfma_f32_16x16x32_bf16(kh_, qfl[ks], sc[nt], 0, 0, 0);
      }
    }
    // ---- online softmax for qrow=l15: in-lane max over 16 keys + 2 shfl ----
    float mx = fmaxf(fmaxf(fmaxf(sc[0][0], sc[0][1]), fmaxf(sc[0][2], sc[0][3])),
                     fmaxf(fmaxf(sc[1][0], sc[1][1]), fmaxf(sc[1][2], sc[1][3])));
    float mx2 = fmaxf(fmaxf(fmaxf(sc[2][0], sc[2][1]), fmaxf(sc[2][2], sc[2][3])),
                      fmaxf(fmaxf(sc[3][0], sc[3][1]), fmaxf(sc[3][2], sc[3][3])));
    mx = fmaxf(mx, mx2);
    mx = fmaxf(mx, __shfl_xor(mx, 16));
    mx = fmaxf(mx, __shfl_xor(mx, 32));
    float mn = fmaxf(mi, mx);
    float alpha_s = exp2f(mi - mn);
    mi = mn;
    // ---- P = exp2(sc - mn), packed ds_write_b64 into lp[qrow][key] (swz64) ----
    u16* lpw = &lp[wave][0];
    int r7 = l15 & 7;
#pragma unroll
    for (int nt = 0; nt < 4; ++nt) {
      float e0 = exp2f(sc[nt][0] - mn);
      float e1 = exp2f(sc[nt][1] - mn);
      float e2 = exp2f(sc[nt][2] - mn);
      float e3 = exp2f(sc[nt][3] - mn);
      unsigned u01 = pk2(e0, e1), u23 = pk2(e2, e3);
      int c = nt * 2 + (quad >> 1);              // unswizzled 16B chunk of key
      int off = l15 * 64 + ((c ^ r7) * 8) + (quad & 1) * 4;
      *(u32x2*)(&lpw[off]) = u32x2{u01, u23};
    }
    // ---- broadcast alpha to O domain (qrow = quad*4+r) and rescale ----
    float av[4];
#pragma unroll
    for (int r = 0; r < 4; ++r) av[r] = __shfl(alpha_s, quad * 4 + r);
#pragma unroll
    for (int r = 0; r < 4; ++r) {
      lsum[r] *= av[r];
      o[0][r] *= av[r]; o[1][r] *= av[r]; o[2][r] *= av[r]; o[3][r] *= av[r];
    }
    // wave-private LDS write->read: drain DS queue (in-order per wave)
    asm volatile("s_waitcnt lgkmcnt(0)" ::: "memory");
    // ---- P @ V (+ ones-B MFMA accumulates the row-sum l) ----
    bf16x8 pa[2];
#pragma unroll
    for (int ks = 0; ks < 2; ++ks)
      pa[ks] = ld8(&lpw[swz64(l15, ks * 4 + quad)]);
    lsum = __builtin_amdgcn_mfma_f32_16x16x32_bf16(pa[0], onesf, lsum, 0, 0, 0);
    lsum = __builtin_amdgcn_mfma_f32_16x16x32_bf16(pa[1], onesf, lsum, 0, 0, 0);
#pragma unroll
    for (int nt = 0; nt < 4; ++nt)
#pragma unroll
      for (int ks = 0; ks < 2; ++ks) {
        bf16x8 bv = ld8(&lvt[swz64(nt * 16 + l15, ks * 4 + quad)]);
        o[nt] = __builtin_amdgcn_mfma_f32_16x16x32_bf16(pa[ks], bv, o[nt], 0, 0, 0);
      }
  }
  // epilogue: out[b, s, h*64+d]
  float inv[4];
#pragma unroll
  for (int r = 0; r < 4; ++r) inv[r] = 1.0f / lsum[r];
#pragma unroll
  for (int nt = 0; nt < 4; ++nt)
#pragma unroll
    for (int r = 0; r < 4; ++r) {
      int srow = q0 + wave * 16 + quad * 4 + r;
      int d = nt * 16 + l15;
      out[(size_t)(b * 2048 + srow) * 1024 + h * 64 + d] = o[nt][r] * inv[r];
    }
}

extern "C" void kernel_launch(void* const* d_in, const int* in_sizes, int n_in,
                              void* d_out, int out_size, void* d_ws, size_t ws_size,
                              hipStream_t stream) {
  const float* q  = (const float*)d_in[0];
  const float* k  = (const float*)d_in[1];
  const float* v  = (const float*)d_in[2];
  const float* Wq = (const float*)d_in[3];
  const float* Wk = (const float*)d_in[4];
  const float* Wv = (const float*)d_in[5];
  u16* ws = (u16*)d_ws;
  float* out = (float*)d_out;

  convert_x3<<<dim3(4096, 3), 256, 0, stream>>>(q, k, v, ws);
  convert_w3<<<dim3(32, 32, 3), 256, 0, stream>>>(Wq, Wk, Wv, ws);
  gemm_qkv<<<768, 256, 0, stream>>>(ws);
  transpose_v<<<dim3(32, 32), 256, 0, stream>>>(ws + OFF_VH, ws + OFF_VT);
  attn<<<dim3(32, 16, 2), 256, 0, stream>>>(ws, out);
}

// Round 7
// 299.513 us; speedup vs baseline: 1.2681x; 1.1634x over previous
//
#include <hip/hip_runtime.h>
#include <cstdint>
#include <cstddef>

typedef unsigned short u16;
typedef __bf16 bf16x8 __attribute__((ext_vector_type(8)));
typedef float f32x4 __attribute__((ext_vector_type(4)));
typedef unsigned int u32x4 __attribute__((ext_vector_type(4)));
typedef unsigned int u32x2 __attribute__((ext_vector_type(2)));
typedef u16 u16x4 __attribute__((ext_vector_type(4)));

typedef __attribute__((address_space(3))) void lds_void;
typedef __attribute__((address_space(1))) void glb_void;

constexpr float CEXP = 92.33248261689366f;   // 64 * log2(e): folded into Q

// ---------------- workspace layout (u16 element offsets) ----------------
constexpr size_t XSZ = 4096ull * 1024ull;   // one [4096,1024] bf16 array
constexpr size_t WSZ = 1024ull * 1024ull;   // one [1024,1024] bf16 array
constexpr size_t OFF_XQH = 0;
constexpr size_t OFF_XQL = OFF_XQH + XSZ;
constexpr size_t OFF_XKH = OFF_XQL + XSZ;
constexpr size_t OFF_XKL = OFF_XKH + XSZ;
constexpr size_t OFF_XVH = OFF_XKL + XSZ;
constexpr size_t OFF_XVL = OFF_XVH + XSZ;
constexpr size_t OFF_WQH = OFF_XVL + XSZ;
constexpr size_t OFF_WQL = OFF_WQH + WSZ;
constexpr size_t OFF_WKH = OFF_WQL + WSZ;
constexpr size_t OFF_WKL = OFF_WKH + WSZ;
constexpr size_t OFF_WVH = OFF_WKL + WSZ;
constexpr size_t OFF_WVL = OFF_WVH + WSZ;
constexpr size_t OFF_QH  = OFF_WVL + WSZ;   // [B,H,S,64]  (pre-scaled by CEXP)
constexpr size_t OFF_QL  = OFF_QH + XSZ;
constexpr size_t OFF_KH  = OFF_QL + XSZ;
constexpr size_t OFF_KL  = OFF_KH + XSZ;
constexpr size_t OFF_VH  = OFF_KL + XSZ;    // [B,H,S,64]
constexpr size_t OFF_VT  = OFF_VH + XSZ;    // [B,H,64,S]

// ---------------- helpers ----------------
__device__ __forceinline__ u16 f2b(float f) {           // fp32 -> bf16 RNE
  unsigned u = __builtin_bit_cast(unsigned, f);
  return (u16)((u + 0x7FFFu + ((u >> 16) & 1u)) >> 16);
}
__device__ __forceinline__ float b2f(u16 h) {
  return __builtin_bit_cast(float, ((unsigned)h) << 16);
}
__device__ __forceinline__ bf16x8 ld8(const u16* p) {   // 16B frag load
  return __builtin_bit_cast(bf16x8, *(const u32x4*)p);
}
__device__ __forceinline__ unsigned pk2(float a, float b) {  // pack 2 bf16 (RNE)
#if __has_builtin(__builtin_amdgcn_cvt_pk_bf16_f32)
  auto v = __builtin_amdgcn_cvt_pk_bf16_f32(a, b);
  return __builtin_bit_cast(unsigned, v);
#else
  return (unsigned)f2b(a) | ((unsigned)f2b(b) << 16);
#endif
}
__device__ __forceinline__ void glds16(const u16* g, u16* l) { // 16B global->LDS
  __builtin_amdgcn_global_load_lds((const glb_void*)g, (lds_void*)l, 16, 0, 0);
}
// swizzled LDS offset for a [rows][32 u16] tile: chunk = 8 u16 (16B)
__device__ __forceinline__ int swz32(int row, int cg) {
  return row * 32 + ((cg ^ ((row >> 1) & 3)) * 8);
}
// swizzled LDS offset for a [rows][64 u16] tile: chunk = 8 u16 (16B)
__device__ __forceinline__ int swz64(int row, int cg) {
  return row * 64 + ((cg ^ (row & 7)) * 8);
}

// ---------------- fused converts: x (hi/lo) + W^T (hi/lo) ----------------
__global__ __launch_bounds__(256) void convert_all(const float* __restrict__ q,
                                                   const float* __restrict__ k,
                                                   const float* __restrict__ v,
                                                   const float* __restrict__ Wq,
                                                   const float* __restrict__ Wk,
                                                   const float* __restrict__ Wv,
                                                   u16* __restrict__ ws) {
  __shared__ float tile[32][33];
  int id = blockIdx.x;
  int t = threadIdx.x;
  if (id < 12288) {                       // ---- x path: 4096 blocks per z ----
    int z = id >> 12, blk = id & 4095;
    const float* in = (z == 0) ? q : (z == 1) ? k : v;
    u16* hi = ws + ((z == 0) ? OFF_XQH : (z == 1) ? OFF_XKH : OFF_XVH);
    u16* lo = ws + ((z == 0) ? OFF_XQL : (z == 1) ? OFF_XKL : OFF_XVL);
    size_t i = ((size_t)blk * 256u + t) * 4u;
    float4 vv = *(const float4*)(in + i);
    float a[4] = {vv.x, vv.y, vv.z, vv.w};
    u16x4 hv, lv;
#pragma unroll
    for (int j = 0; j < 4; ++j) {
      u16 hb = f2b(a[j]);
      hv[j] = hb;
      lv[j] = f2b(a[j] - b2f(hb));
    }
    *(u16x4*)(hi + i) = hv;
    *(u16x4*)(lo + i) = lv;
  } else {                                // ---- W path: 1024 blocks per z ----
    int r0 = id - 12288;
    int z = r0 >> 10, rem = r0 & 1023;
    const float* W = (z == 0) ? Wq : (z == 1) ? Wk : Wv;
    u16* hiT = ws + ((z == 0) ? OFF_WQH : (z == 1) ? OFF_WKH : OFF_WVH);
    u16* loT = ws + ((z == 0) ? OFF_WQL : (z == 1) ? OFF_WKL : OFF_WVL);
    int n0 = (rem & 31) * 32, k0 = (rem >> 5) * 32;
    int r = t >> 3, c0 = (t & 7) * 4;
    float4 vv = *(const float4*)(W + (size_t)(k0 + r) * 1024 + n0 + c0);
    tile[r][c0] = vv.x; tile[r][c0 + 1] = vv.y; tile[r][c0 + 2] = vv.z; tile[r][c0 + 3] = vv.w;
    __syncthreads();
    u16x4 hv, lv;
#pragma unroll
    for (int j = 0; j < 4; ++j) {
      float x = tile[c0 + j][r];          // = W[k0+c0+j][n0+r]
      u16 hb = f2b(x);
      hv[j] = hb;
      lv[j] = f2b(x - b2f(hb));
    }
    size_t o = (size_t)(n0 + r) * 1024 + k0 + c0;
    *(u16x4*)(hiT + o) = hv;
    *(u16x4*)(loT + o) = lv;
  }
}

// ---------------- QKV projection GEMM, 64x128 tile, 4 waves ------------------
// 1536 blocks, XCD-balanced: pair = (seq>>3)*8 + xcd gives every XCD 8 Q + 8 K
// + 8 V tile-rows (equal work), and all 8 n-blocks of a tile-row stay on ONE
// XCD (A-row fetched from HBM once; W re-reads served by L3).
// 64x128 tile => acc is 8 f32x4 per wave (32 regs): ~122 total regs/wave ->
// 4 waves/SIMD, ~4 blocks/CU resident to interleave the per-iter vmcnt drains
// (R6: 208 regs -> 2 waves/SIMD -> latency-bound at 17% MfmaUtil).
// z=0: Q = hi*hi+lo*hi+hi*lo (hi/lo out, scaled CEXP); z=1: K same; z=2: V hi.
__global__ __launch_bounds__(256, 4) void gemm_qkv(u16* __restrict__ ws) {
  __shared__ u16 sA[2][64 * 32];      // hi/lo A: 4 KB each
  __shared__ u16 sB[2][128 * 32];     // hi/lo B: 8 KB each; reused as C buffer
  u16* cbuf = &sB[0][0];              // 64x128 u16 = 16 KB epilogue view

  int id = blockIdx.x;
  int xcd = id & 7, seq = id >> 3;          // assume round-robin dispatch
  int pair = (seq >> 3) * 8 + xcd;          // 0..191, z-balanced per XCD
  int tile_n = seq & 7;
  int z = pair >> 6;                        // pair / 64
  int tile_m = pair & 63;

  const u16 *Ah, *Al, *Bh, *Bl; u16 *Oh, *Ol; bool split;
  if (z == 0)      { Ah = ws + OFF_XQH; Al = ws + OFF_XQL; Bh = ws + OFF_WQH; Bl = ws + OFF_WQL; Oh = ws + OFF_QH; Ol = ws + OFF_QL; split = true; }
  else if (z == 1) { Ah = ws + OFF_XKH; Al = ws + OFF_XKL; Bh = ws + OFF_WKH; Bl = ws + OFF_WKL; Oh = ws + OFF_KH; Ol = ws + OFF_KL; split = true; }
  else             { Ah = ws + OFF_XVH; Al = nullptr;      Bh = ws + OFF_WVH; Bl = nullptr;      Oh = ws + OFF_VH; Ol = nullptr;    split = false; }
  float oscale = (z == 0) ? CEXP : 1.0f;
  int m0 = tile_m * 64, n0 = tile_n * 128;
  int t = threadIdx.x, lane = t & 63, wave = t >> 6;
  int quad = lane >> 4, l15 = lane & 15;
  int wm = (wave >> 1) * 32, wn = (wave & 1) * 64;
  int rl = lane >> 2, cgl = lane & 3;       // staging: 16 rows x 4 chunks/issue
  f32x4 acc[2][4] = {};

  // hoisted staging addresses (k0 added in-loop)
  int rowA = wave * 16 + rl;
  size_t gA = (size_t)(m0 + rowA) * 1024 + (cgl ^ ((rowA >> 1) & 3)) * 8;
  int lbA = wave * 512;
  size_t gB[2]; int lbB[2];
#pragma unroll
  for (int i = 0; i < 2; ++i) {
    int rowB = wave * 32 + i * 16 + rl;
    gB[i] = (size_t)(n0 + rowB) * 1024 + (cgl ^ ((rowB >> 1) & 3)) * 8;
    lbB[i] = wave * 1024 + i * 512;
  }

  for (int kb = 0; kb < 32; ++kb) {
    int k0 = kb * 32;
    __syncthreads();
    glds16(Ah + gA + k0, &sA[0][lbA]);
    if (split) glds16(Al + gA + k0, &sA[1][lbA]);
#pragma unroll
    for (int i = 0; i < 2; ++i) {
      glds16(Bh + gB[i] + k0, &sB[0][lbB[i]]);
      if (split) glds16(Bl + gB[i] + k0, &sB[1][lbB[i]]);
    }
    __syncthreads();
    bf16x8 afh[2], afl[2], bfh[4], bfl[4];
#pragma unroll
    for (int mt = 0; mt < 2; ++mt) {
      int ra = wm + mt * 16 + l15;
      afh[mt] = ld8(&sA[0][swz32(ra, quad)]);
      if (split) afl[mt] = ld8(&sA[1][swz32(ra, quad)]);
    }
#pragma unroll
    for (int nt = 0; nt < 4; ++nt) {
      int rb = wn + nt * 16 + l15;
      bfh[nt] = ld8(&sB[0][swz32(rb, quad)]);
      if (split) bfl[nt] = ld8(&sB[1][swz32(rb, quad)]);
    }
#pragma unroll
    for (int mt = 0; mt < 2; ++mt)
#pragma unroll
      for (int nt = 0; nt < 4; ++nt) {
        acc[mt][nt] = __builtin_amdgcn_mfma_f32_16x16x32_bf16(afh[mt], bfh[nt], acc[mt][nt], 0, 0, 0);
        if (split) {
          acc[mt][nt] = __builtin_amdgcn_mfma_f32_16x16x32_bf16(afl[mt], bfh[nt], acc[mt][nt], 0, 0, 0);
          acc[mt][nt] = __builtin_amdgcn_mfma_f32_16x16x32_bf16(afh[mt], bfl[nt], acc[mt][nt], 0, 0, 0);
        }
      }
  }
  // ---- LDS-staged coalesced epilogue (cbuf = 64 rows x 16 chunks, XOR swz) ----
  auto epi_round = [&](u16* dst, bool lo_round) {
#pragma unroll
    for (int mt = 0; mt < 2; ++mt)
#pragma unroll
      for (int nt = 0; nt < 4; ++nt)
#pragma unroll
        for (int r = 0; r < 4; ++r) {
          int row = wm + mt * 16 + quad * 4 + r;
          int col = wn + nt * 16 + l15;
          float v = acc[mt][nt][r] * oscale;
          u16 hb = f2b(v);
          u16 val = lo_round ? f2b(v - b2f(hb)) : hb;
          cbuf[row * 128 + (((col >> 3) ^ (row & 15)) * 8) + (col & 7)] = val;
        }
    __syncthreads();
    // each thread stores one 64B run: (row, quarter) -> out[.., s, d0..d0+31]
    int row = t >> 2, seg = t & 3;
    int gm = m0 + row, bb = gm >> 11, s = gm & 2047;
    int hh = (n0 >> 6) + (seg >> 1), d0 = (seg & 1) * 32;
    u16* gp = dst + ((size_t)(bb * 16 + hh) * 2048 + s) * 64 + d0;
#pragma unroll
    for (int i = 0; i < 4; ++i) {
      int phys = (seg * 4 + i) ^ (row & 15);
      *(u32x4*)(gp + i * 8) = *(const u32x4*)(&cbuf[row * 128 + phys * 8]);
    }
  };
  __syncthreads();                 // staging reads done; cbuf free
  epi_round(Oh, false);
  if (split) {
    __syncthreads();
    epi_round(Ol, true);
  }
}

// ---------------- V [B,H,S,64] -> Vt [B,H,64,S] ----------------
__global__ __launch_bounds__(256) void transpose_v(const u16* __restrict__ vh,
                                                   u16* __restrict__ vt) {
  __shared__ u16 tile[64][72];
  int bh = blockIdx.y;                 // b*16+h
  int s0 = blockIdx.x * 64;
  int t = threadIdx.x;
  for (int c = t; c < 512; c += 256) {
    int row = c >> 3, off = (c & 7) * 8;
    *(u32x4*)(&tile[row][off]) = *(const u32x4*)(vh + ((size_t)bh * 2048 + s0 + row) * 64 + off);
  }
  __syncthreads();
  int d = t >> 2, i0 = (t & 3) * 16;
  u16 vals[16];
#pragma unroll
  for (int i = 0; i < 16; ++i) vals[i] = tile[i0 + i][d];
  u16* outp = vt + ((size_t)bh * 64 + d) * 2048 + s0 + i0;
  *(u32x4*)(outp)     = *(u32x4*)(&vals[0]);
  *(u32x4*)(outp + 8) = *(u32x4*)(&vals[8]);
}

// ---------------- flash attention: 64 Q-rows/block, 64-key tiles -------------
// R3-measured version (125 us): single-buffer 2-barrier K-loop, QK^T operand-
// SWAPPED (sc = K_frag x Q_frag = S^T[key][qrow]) so each lane holds 4
// consecutive keys of ONE qrow: cheap max-reduce (2 shfl) + packed P stores.
__global__ __launch_bounds__(256) void attn(const u16* __restrict__ ws,
                                            float* __restrict__ out) {
  __shared__ u16 lkh[64 * 64];
  __shared__ u16 lkl[64 * 64];
  __shared__ u16 lvt[64 * 64];
  __shared__ u16 lp[4][16 * 64];     // per-wave P tile [qrow][key], swz64
  const u16* Qh = ws + OFF_QH; const u16* Ql = ws + OFF_QL;
  const u16* Kh = ws + OFF_KH; const u16* Kl = ws + OFF_KL;
  const u16* Vt = ws + OFF_VT;
  int b = blockIdx.z, h = blockIdx.y;
  int q0 = blockIdx.x * 64;
  int t = threadIdx.x, lane = t & 63, wave = t >> 6;
  int quad = lane >> 4, l15 = lane & 15;
  size_t hb = (size_t)(b * 16 + h) * (2048 * 64);
  bf16x8 onesf;                                  // ones B-frag for row-sum MFMA
#pragma unroll
  for (int j = 0; j < 8; ++j) onesf[j] = __builtin_bit_cast(__bf16, (u16)0x3F80);
  // Q fragments (B operand: lane holds qrow=lane&15, 8 consecutive d)
  int qrow = q0 + wave * 16 + l15;
  bf16x8 qfh[2], qfl[2];
#pragma unroll
  for (int ks = 0; ks < 2; ++ks) {
    size_t qo = hb + (size_t)qrow * 64 + ks * 32 + quad * 8;
    qfh[ks] = ld8(Qh + qo);
    qfl[ks] = ld8(Ql + qo);
  }
  float mi = -1e30f;                 // running max for qrow=l15 (St domain)
  f32x4 lsum = {};                   // row-sum accumulator (O domain)
  f32x4 o[4] = {};
  int rl = lane >> 3, cgl = lane & 7;            // staging: 8 rows x 8 chunks/issue

  for (int kt = 0; kt < 32; ++kt) {
    __syncthreads();
#pragma unroll
    for (int i = 0; i < 2; ++i) {
      int row = wave * 16 + i * 8 + rl;          // tile-local row 0..63
      int cgg = cgl ^ (row & 7);
      int lbase = (wave * 16 + i * 8) * 64;      // wave-uniform
      size_t gk = hb + (size_t)(kt * 64 + row) * 64 + cgg * 8;   // K: [key][d]
      glds16(Kh + gk, &lkh[lbase]);
      glds16(Kl + gk, &lkl[lbase]);
      size_t gv = hb + (size_t)row * 2048 + kt * 64 + cgg * 8;   // Vt: [d][key]
      glds16(Vt + gv, &lvt[lbase]);
    }
    __syncthreads();
    // ---- QK^T (swapped): sc[nt] = S^T block, rows=keys nt*16+quad*4+r, col=qrow=l15
    f32x4 sc[4] = {};
#pragma unroll
    for (int nt = 0; nt < 4; ++nt) {
#pragma unroll
      for (int ks = 0; ks < 2; ++ks) {
        int so = swz64(nt * 16 + l15, ks * 4 + quad);
        bf16x8 kh_ = ld8(&lkh[so]);
        bf16x8 kl_ = ld8(&lkl[so]);
        sc[nt] = __builtin_amdgcn_mfma_f32_16x16x32_bf16(kh_, qfh[ks], sc[nt], 0, 0, 0);
        sc[nt] = __builtin_amdgcn_mfma_f32_16x16x32_bf16(kl_, qfh[ks], sc[nt], 0, 0, 0);
        sc[nt] = __builtin_amdgcn_mfma_f32_16x16x32_bf16(kh_, qfl[ks], sc[nt], 0, 0, 0);
      }
    }
    // ---- online softmax for qrow=l15: in-lane max over 16 keys + 2 shfl ----
    float mx = fmaxf(fmaxf(fmaxf(sc[0][0], sc[0][1]), fmaxf(sc[0][2], sc[0][3])),
                     fmaxf(fmaxf(sc[1][0], sc[1][1]), fmaxf(sc[1][2], sc[1][3])));
    float mx2 = fmaxf(fmaxf(fmaxf(sc[2][0], sc[2][1]), fmaxf(sc[2][2], sc[2][3])),
                      fmaxf(fmaxf(sc[3][0], sc[3][1]), fmaxf(sc[3][2], sc[3][3])));
    mx = fmaxf(mx, mx2);
    mx = fmaxf(mx, __shfl_xor(mx, 16));
    mx = fmaxf(mx, __shfl_xor(mx, 32));
    float mn = fmaxf(mi, mx);
    float alpha_s = exp2f(mi - mn);
    mi = mn;
    // ---- P = exp2(sc - mn), packed ds_write_b64 into lp[qrow][key] (swz64) ----
    u16* lpw = &lp[wave][0];
    int r7 = l15 & 7;
#pragma unroll
    for (int nt = 0; nt < 4; ++nt) {
      float e0 = exp2f(sc[nt][0] - mn);
      float e1 = exp2f(sc[nt][1] - mn);
      float e2 = exp2f(sc[nt][2] - mn);
      float e3 = exp2f(sc[nt][3] - mn);
      unsigned u01 = pk2(e0, e1), u23 = pk2(e2, e3);
      int c = nt * 2 + (quad >> 1);              // unswizzled 16B chunk of key
      int off = l15 * 64 + ((c ^ r7) * 8) + (quad & 1) * 4;
      *(u32x2*)(&lpw[off]) = u32x2{u01, u23};
    }
    // ---- broadcast alpha to O domain (qrow = quad*4+r) and rescale ----
    float av[4];
#pragma unroll
    for (int r = 0; r < 4; ++r) av[r] = __shfl(alpha_s, quad * 4 + r);
#pragma unroll
    for (int r = 0; r < 4; ++r) {
      lsum[r] *= av[r];
      o[0][r] *= av[r]; o[1][r] *= av[r]; o[2][r] *= av[r]; o[3][r] *= av[r];
    }
    // wave-private LDS write->read: drain DS queue (in-order per wave)
    asm volatile("s_waitcnt lgkmcnt(0)" ::: "memory");
    // ---- P @ V (+ ones-B MFMA accumulates the row-sum l) ----
    bf16x8 pa[2];
#pragma unroll
    for (int ks = 0; ks < 2; ++ks)
      pa[ks] = ld8(&lpw[swz64(l15, ks * 4 + quad)]);
    lsum = __builtin_amdgcn_mfma_f32_16x16x32_bf16(pa[0], onesf, lsum, 0, 0, 0);
    lsum = __builtin_amdgcn_mfma_f32_16x16x32_bf16(pa[1], onesf, lsum, 0, 0, 0);
#pragma unroll
    for (int nt = 0; nt < 4; ++nt)
#pragma unroll
      for (int ks = 0; ks < 2; ++ks) {
        bf16x8 bv = ld8(&lvt[swz64(nt * 16 + l15, ks * 4 + quad)]);
        o[nt] = __builtin_amdgcn_mfma_f32_16x16x32_bf16(pa[ks], bv, o[nt], 0, 0, 0);
      }
  }
  // epilogue: out[b, s, h*64+d]
  float inv[4];
#pragma unroll
  for (int r = 0; r < 4; ++r) inv[r] = 1.0f / lsum[r];
#pragma unroll
  for (int nt = 0; nt < 4; ++nt)
#pragma unroll
    for (int r = 0; r < 4; ++r) {
      int srow = q0 + wave * 16 + quad * 4 + r;
      int d = nt * 16 + l15;
      out[(size_t)(b * 2048 + srow) * 1024 + h * 64 + d] = o[nt][r] * inv[r];
    }
}

extern "C" void kernel_launch(void* const* d_in, const int* in_sizes, int n_in,
                              void* d_out, int out_size, void* d_ws, size_t ws_size,
                              hipStream_t stream) {
  const float* q  = (const float*)d_in[0];
  const float* k  = (const float*)d_in[1];
  const float* v  = (const float*)d_in[2];
  const float* Wq = (const float*)d_in[3];
  const float* Wk = (const float*)d_in[4];
  const float* Wv = (const float*)d_in[5];
  u16* ws = (u16*)d_ws;
  float* out = (float*)d_out;

  convert_all<<<15360, 256, 0, stream>>>(q, k, v, Wq, Wk, Wv, ws);
  gemm_qkv<<<1536, 256, 0, stream>>>(ws);
  transpose_v<<<dim3(32, 32), 256, 0, stream>>>(ws + OFF_VH, ws + OFF_VT);
  attn<<<dim3(32, 16, 2), 256, 0, stream>>>(ws, out);
}

// Round 8
// 281.104 us; speedup vs baseline: 1.3512x; 1.0655x over previous
//
#include <hip/hip_runtime.h>
#include <cstdint>
#include <cstddef>

typedef unsigned short u16;
typedef __bf16 bf16x8 __attribute__((ext_vector_type(8)));
typedef float f32x4 __attribute__((ext_vector_type(4)));
typedef unsigned int u32x4 __attribute__((ext_vector_type(4)));
typedef unsigned int u32x2 __attribute__((ext_vector_type(2)));
typedef u16 u16x4 __attribute__((ext_vector_type(4)));

typedef __attribute__((address_space(3))) void lds_void;
typedef __attribute__((address_space(1))) void glb_void;

constexpr float CEXP = 92.33248261689366f;   // 64 * log2(e): folded into Q

// ---------------- workspace layout (u16 element offsets) ----------------
constexpr size_t XSZ = 4096ull * 1024ull;   // one [4096,1024] bf16 array
constexpr size_t WSZ = 1024ull * 1024ull;   // one [1024,1024] bf16 array
constexpr size_t OFF_XQH = 0;
constexpr size_t OFF_XQL = OFF_XQH + XSZ;
constexpr size_t OFF_XKH = OFF_XQL + XSZ;
constexpr size_t OFF_XKL = OFF_XKH + XSZ;
constexpr size_t OFF_XVH = OFF_XKL + XSZ;
constexpr size_t OFF_XVL = OFF_XVH + XSZ;
constexpr size_t OFF_WQH = OFF_XVL + XSZ;
constexpr size_t OFF_WQL = OFF_WQH + WSZ;
constexpr size_t OFF_WKH = OFF_WQL + WSZ;
constexpr size_t OFF_WKL = OFF_WKH + WSZ;
constexpr size_t OFF_WVH = OFF_WKL + WSZ;
constexpr size_t OFF_WVL = OFF_WVH + WSZ;
constexpr size_t OFF_QH  = OFF_WVL + WSZ;   // [B,H,S,64]  (pre-scaled by CEXP)
constexpr size_t OFF_QL  = OFF_QH + XSZ;
constexpr size_t OFF_KH  = OFF_QL + XSZ;
constexpr size_t OFF_KL  = OFF_KH + XSZ;
constexpr size_t OFF_VH  = OFF_KL + XSZ;    // [B,H,S,64]
constexpr size_t OFF_VT  = OFF_VH + XSZ;    // [B,H,64,S]

// ---------------- helpers ----------------
__device__ __forceinline__ u16 f2b(float f) {           // fp32 -> bf16 RNE
  unsigned u = __builtin_bit_cast(unsigned, f);
  return (u16)((u + 0x7FFFu + ((u >> 16) & 1u)) >> 16);
}
__device__ __forceinline__ float b2f(u16 h) {
  return __builtin_bit_cast(float, ((unsigned)h) << 16);
}
__device__ __forceinline__ bf16x8 ld8(const u16* p) {   // 16B frag load
  return __builtin_bit_cast(bf16x8, *(const u32x4*)p);
}
__device__ __forceinline__ unsigned pk2(float a, float b) {  // pack 2 bf16 (RNE)
#if __has_builtin(__builtin_amdgcn_cvt_pk_bf16_f32)
  auto v = __builtin_amdgcn_cvt_pk_bf16_f32(a, b);
  return __builtin_bit_cast(unsigned, v);
#else
  return (unsigned)f2b(a) | ((unsigned)f2b(b) << 16);
#endif
}
__device__ __forceinline__ float ex2(float x) {         // raw v_exp_f32
#if __has_builtin(__builtin_amdgcn_exp2f)
  return __builtin_amdgcn_exp2f(x);
#else
  return exp2f(x);
#endif
}
__device__ __forceinline__ void glds16(const u16* g, u16* l) { // 16B global->LDS
  __builtin_amdgcn_global_load_lds((const glb_void*)g, (lds_void*)l, 16, 0, 0);
}
// swizzled LDS offset for a [rows][32 u16] tile: chunk = 8 u16 (16B)
__device__ __forceinline__ int swz32(int row, int cg) {
  return row * 32 + ((cg ^ ((row >> 1) & 3)) * 8);
}
// swizzled LDS offset for a [rows][64 u16] tile: chunk = 8 u16 (16B)
__device__ __forceinline__ int swz64(int row, int cg) {
  return row * 64 + ((cg ^ (row & 7)) * 8);
}

// ---------------- fused converts: x (hi/lo) + W^T (hi/lo) ----------------
__global__ __launch_bounds__(256) void convert_all(const float* __restrict__ q,
                                                   const float* __restrict__ k,
                                                   const float* __restrict__ v,
                                                   const float* __restrict__ Wq,
                                                   const float* __restrict__ Wk,
                                                   const float* __restrict__ Wv,
                                                   u16* __restrict__ ws) {
  __shared__ float tile[32][33];
  int id = blockIdx.x;
  int t = threadIdx.x;
  if (id < 12288) {                       // ---- x path: 4096 blocks per z ----
    int z = id >> 12, blk = id & 4095;
    const float* in = (z == 0) ? q : (z == 1) ? k : v;
    u16* hi = ws + ((z == 0) ? OFF_XQH : (z == 1) ? OFF_XKH : OFF_XVH);
    u16* lo = ws + ((z == 0) ? OFF_XQL : (z == 1) ? OFF_XKL : OFF_XVL);
    size_t i = ((size_t)blk * 256u + t) * 4u;
    float4 vv = *(const float4*)(in + i);
    float a[4] = {vv.x, vv.y, vv.z, vv.w};
    u16x4 hv, lv;
#pragma unroll
    for (int j = 0; j < 4; ++j) {
      u16 hb = f2b(a[j]);
      hv[j] = hb;
      lv[j] = f2b(a[j] - b2f(hb));
    }
    *(u16x4*)(hi + i) = hv;
    *(u16x4*)(lo + i) = lv;
  } else {                                // ---- W path: 1024 blocks per z ----
    int r0 = id - 12288;
    int z = r0 >> 10, rem = r0 & 1023;
    const float* W = (z == 0) ? Wq : (z == 1) ? Wk : Wv;
    u16* hiT = ws + ((z == 0) ? OFF_WQH : (z == 1) ? OFF_WKH : OFF_WVH);
    u16* loT = ws + ((z == 0) ? OFF_WQL : (z == 1) ? OFF_WKL : OFF_WVL);
    int n0 = (rem & 31) * 32, k0 = (rem >> 5) * 32;
    int r = t >> 3, c0 = (t & 7) * 4;
    float4 vv = *(const float4*)(W + (size_t)(k0 + r) * 1024 + n0 + c0);
    tile[r][c0] = vv.x; tile[r][c0 + 1] = vv.y; tile[r][c0 + 2] = vv.z; tile[r][c0 + 3] = vv.w;
    __syncthreads();
    u16x4 hv, lv;
#pragma unroll
    for (int j = 0; j < 4; ++j) {
      float x = tile[c0 + j][r];          // = W[k0+c0+j][n0+r]
      u16 hb = f2b(x);
      hv[j] = hb;
      lv[j] = f2b(x - b2f(hb));
    }
    size_t o = (size_t)(n0 + r) * 1024 + k0 + c0;
    *(u16x4*)(hiT + o) = hv;
    *(u16x4*)(loT + o) = lv;
  }
}

// ---------------- QKV projection GEMM, 64x128 tile, 4 waves ------------------
// 1536 blocks, XCD-balanced: pair = (seq>>3)*8 + xcd gives every XCD 8 Q + 8 K
// + 8 V tile-rows (equal work), and all 8 n-blocks of a tile-row stay on ONE
// XCD (A-row fetched from HBM once; W re-reads served by L3).
__global__ __launch_bounds__(256, 4) void gemm_qkv(u16* __restrict__ ws) {
  __shared__ u16 sA[2][64 * 32];      // hi/lo A: 4 KB each
  __shared__ u16 sB[2][128 * 32];     // hi/lo B: 8 KB each; reused as C buffer
  u16* cbuf = &sB[0][0];              // 64x128 u16 = 16 KB epilogue view

  int id = blockIdx.x;
  int xcd = id & 7, seq = id >> 3;          // assume round-robin dispatch
  int pair = (seq >> 3) * 8 + xcd;          // 0..191, z-balanced per XCD
  int tile_n = seq & 7;
  int z = pair >> 6;                        // pair / 64
  int tile_m = pair & 63;

  const u16 *Ah, *Al, *Bh, *Bl; u16 *Oh, *Ol; bool split;
  if (z == 0)      { Ah = ws + OFF_XQH; Al = ws + OFF_XQL; Bh = ws + OFF_WQH; Bl = ws + OFF_WQL; Oh = ws + OFF_QH; Ol = ws + OFF_QL; split = true; }
  else if (z == 1) { Ah = ws + OFF_XKH; Al = ws + OFF_XKL; Bh = ws + OFF_WKH; Bl = ws + OFF_WKL; Oh = ws + OFF_KH; Ol = ws + OFF_KL; split = true; }
  else             { Ah = ws + OFF_XVH; Al = nullptr;      Bh = ws + OFF_WVH; Bl = nullptr;      Oh = ws + OFF_VH; Ol = nullptr;    split = false; }
  float oscale = (z == 0) ? CEXP : 1.0f;
  int m0 = tile_m * 64, n0 = tile_n * 128;
  int t = threadIdx.x, lane = t & 63, wave = t >> 6;
  int quad = lane >> 4, l15 = lane & 15;
  int wm = (wave >> 1) * 32, wn = (wave & 1) * 64;
  int rl = lane >> 2, cgl = lane & 3;       // staging: 16 rows x 4 chunks/issue
  f32x4 acc[2][4] = {};

  // hoisted staging addresses (k0 added in-loop)
  int rowA = wave * 16 + rl;
  size_t gA = (size_t)(m0 + rowA) * 1024 + (cgl ^ ((rowA >> 1) & 3)) * 8;
  int lbA = wave * 512;
  size_t gB[2]; int lbB[2];
#pragma unroll
  for (int i = 0; i < 2; ++i) {
    int rowB = wave * 32 + i * 16 + rl;
    gB[i] = (size_t)(n0 + rowB) * 1024 + (cgl ^ ((rowB >> 1) & 3)) * 8;
    lbB[i] = wave * 1024 + i * 512;
  }

  for (int kb = 0; kb < 32; ++kb) {
    int k0 = kb * 32;
    __syncthreads();
    glds16(Ah + gA + k0, &sA[0][lbA]);
    if (split) glds16(Al + gA + k0, &sA[1][lbA]);
#pragma unroll
    for (int i = 0; i < 2; ++i) {
      glds16(Bh + gB[i] + k0, &sB[0][lbB[i]]);
      if (split) glds16(Bl + gB[i] + k0, &sB[1][lbB[i]]);
    }
    __syncthreads();
    bf16x8 afh[2], afl[2], bfh[4], bfl[4];
#pragma unroll
    for (int mt = 0; mt < 2; ++mt) {
      int ra = wm + mt * 16 + l15;
      afh[mt] = ld8(&sA[0][swz32(ra, quad)]);
      if (split) afl[mt] = ld8(&sA[1][swz32(ra, quad)]);
    }
#pragma unroll
    for (int nt = 0; nt < 4; ++nt) {
      int rb = wn + nt * 16 + l15;
      bfh[nt] = ld8(&sB[0][swz32(rb, quad)]);
      if (split) bfl[nt] = ld8(&sB[1][swz32(rb, quad)]);
    }
#pragma unroll
    for (int mt = 0; mt < 2; ++mt)
#pragma unroll
      for (int nt = 0; nt < 4; ++nt) {
        acc[mt][nt] = __builtin_amdgcn_mfma_f32_16x16x32_bf16(afh[mt], bfh[nt], acc[mt][nt], 0, 0, 0);
        if (split) {
          acc[mt][nt] = __builtin_amdgcn_mfma_f32_16x16x32_bf16(afl[mt], bfh[nt], acc[mt][nt], 0, 0, 0);
          acc[mt][nt] = __builtin_amdgcn_mfma_f32_16x16x32_bf16(afh[mt], bfl[nt], acc[mt][nt], 0, 0, 0);
        }
      }
  }
  // ---- LDS-staged coalesced epilogue (cbuf = 64 rows x 16 chunks, XOR swz) ----
  auto epi_round = [&](u16* dst, bool lo_round) {
#pragma unroll
    for (int mt = 0; mt < 2; ++mt)
#pragma unroll
      for (int nt = 0; nt < 4; ++nt)
#pragma unroll
        for (int r = 0; r < 4; ++r) {
          int row = wm + mt * 16 + quad * 4 + r;
          int col = wn + nt * 16 + l15;
          float v = acc[mt][nt][r] * oscale;
          u16 hb = f2b(v);
          u16 val = lo_round ? f2b(v - b2f(hb)) : hb;
          cbuf[row * 128 + (((col >> 3) ^ (row & 15)) * 8) + (col & 7)] = val;
        }
    __syncthreads();
    // each thread stores one 64B run: (row, quarter) -> out[.., s, d0..d0+31]
    int row = t >> 2, seg = t & 3;
    int gm = m0 + row, bb = gm >> 11, s = gm & 2047;
    int hh = (n0 >> 6) + (seg >> 1), d0 = (seg & 1) * 32;
    u16* gp = dst + ((size_t)(bb * 16 + hh) * 2048 + s) * 64 + d0;
#pragma unroll
    for (int i = 0; i < 4; ++i) {
      int phys = (seg * 4 + i) ^ (row & 15);
      *(u32x4*)(gp + i * 8) = *(const u32x4*)(&cbuf[row * 128 + phys * 8]);
    }
  };
  __syncthreads();                 // staging reads done; cbuf free
  epi_round(Oh, false);
  if (split) {
    __syncthreads();
    epi_round(Ol, true);
  }
}

// ---------------- V [B,H,S,64] -> Vt [B,H,64,S] ----------------
__global__ __launch_bounds__(256) void transpose_v(const u16* __restrict__ vh,
                                                   u16* __restrict__ vt) {
  __shared__ u16 tile[64][72];
  int bh = blockIdx.y;                 // b*16+h
  int s0 = blockIdx.x * 64;
  int t = threadIdx.x;
  for (int c = t; c < 512; c += 256) {
    int row = c >> 3, off = (c & 7) * 8;
    *(u32x4*)(&tile[row][off]) = *(const u32x4*)(vh + ((size_t)bh * 2048 + s0 + row) * 64 + off);
  }
  __syncthreads();
  int d = t >> 2, i0 = (t & 3) * 16;
  u16 vals[16];
#pragma unroll
  for (int i = 0; i < 16; ++i) vals[i] = tile[i0 + i][d];
  u16* outp = vt + ((size_t)bh * 64 + d) * 2048 + s0 + i0;
  *(u32x4*)(outp)     = *(u32x4*)(&vals[0]);
  *(u32x4*)(outp + 8) = *(u32x4*)(&vals[8]);
}

// ---------------- flash attention: 64 Q-rows/block, 64-key tiles -------------
// R3 structure (single-buffer 2-barrier K-loop, QK^T operand-SWAPPED so each
// lane holds 4 consecutive keys of ONE qrow). R8: all loop-invariant LDS
// offsets + staging addresses hoisted into registers, and
// __launch_bounds__(256,5) caps VGPRs at ~102 = exactly the 5 waves/SIMD the
// 32 KB LDS already limits us to (R7 counters: VGPR=64 -> compiler was
// rematerializing ~90 address insts/iter for an 8-waves/SIMD target that LDS
// makes unreachable).
__global__ __launch_bounds__(256, 5) void attn(const u16* __restrict__ ws,
                                               float* __restrict__ out) {
  __shared__ u16 lkh[64 * 64];
  __shared__ u16 lkl[64 * 64];
  __shared__ u16 lvt[64 * 64];
  __shared__ u16 lp[4][16 * 64];     // per-wave P tile [qrow][key], swz64
  const u16* Qh = ws + OFF_QH; const u16* Ql = ws + OFF_QL;
  const u16* Kh = ws + OFF_KH; const u16* Kl = ws + OFF_KL;
  const u16* Vt = ws + OFF_VT;
  int b = blockIdx.z, h = blockIdx.y;
  int q0 = blockIdx.x * 64;
  int t = threadIdx.x, lane = t & 63, wave = t >> 6;
  int quad = lane >> 4, l15 = lane & 15;
  size_t hb = (size_t)(b * 16 + h) * (2048 * 64);
  bf16x8 onesf;                                  // ones B-frag for row-sum MFMA
#pragma unroll
  for (int j = 0; j < 8; ++j) onesf[j] = __builtin_bit_cast(__bf16, (u16)0x3F80);
  // Q fragments (B operand: lane holds qrow=lane&15, 8 consecutive d)
  int qrow = q0 + wave * 16 + l15;
  bf16x8 qfh[2], qfl[2];
#pragma unroll
  for (int ks = 0; ks < 2; ++ks) {
    size_t qo = hb + (size_t)qrow * 64 + ks * 32 + quad * 8;
    qfh[ks] = ld8(Qh + qo);
    qfl[ks] = ld8(Ql + qo);
  }
  float mi = -1e30f;                 // running max for qrow=l15 (St domain)
  f32x4 lsum = {};                   // row-sum accumulator (O domain)
  f32x4 o[4] = {};
  int rl = lane >> 3, cgl = lane & 7;            // staging: 8 rows x 8 chunks/issue

  // ---- hoisted loop-invariant addresses ----
  size_t aK[2], aV[2]; int lb[2];
#pragma unroll
  for (int i = 0; i < 2; ++i) {
    int row = wave * 16 + i * 8 + rl;            // tile-local row 0..63
    int cgg = cgl ^ (row & 7);
    aK[i] = hb + (size_t)row * 64 + cgg * 8;     // + kt*4096 in-loop
    aV[i] = hb + (size_t)row * 2048 + cgg * 8;   // + kt*64  in-loop
    lb[i] = (wave * 16 + i * 8) * 64;
  }
  int soF[2][4];                                  // K/V frag read offsets
#pragma unroll
  for (int ks = 0; ks < 2; ++ks)
#pragma unroll
    for (int nt = 0; nt < 4; ++nt)
      soF[ks][nt] = swz64(nt * 16 + l15, ks * 4 + quad);
  int soP[4];                                     // P store offsets
  {
    int r7 = l15 & 7;
#pragma unroll
    for (int nt = 0; nt < 4; ++nt) {
      int c = nt * 2 + (quad >> 1);
      soP[nt] = l15 * 64 + ((c ^ r7) * 8) + (quad & 1) * 4;
    }
  }
  int soPa[2];                                    // P frag read offsets
#pragma unroll
  for (int ks = 0; ks < 2; ++ks) soPa[ks] = swz64(l15, ks * 4 + quad);
  u16* lpw = &lp[wave][0];

  for (int kt = 0; kt < 32; ++kt) {
    __syncthreads();
#pragma unroll
    for (int i = 0; i < 2; ++i) {
      glds16(Kh + aK[i] + kt * 4096, &lkh[lb[i]]);
      glds16(Kl + aK[i] + kt * 4096, &lkl[lb[i]]);
      glds16(Vt + aV[i] + kt * 64,   &lvt[lb[i]]);
    }
    __syncthreads();
    // ---- QK^T (swapped): sc[nt] rows=keys nt*16+quad*4+r, col=qrow=l15 ----
    f32x4 sc[4] = {};
#pragma unroll
    for (int nt = 0; nt < 4; ++nt) {
#pragma unroll
      for (int ks = 0; ks < 2; ++ks) {
        bf16x8 kh_ = ld8(&lkh[soF[ks][nt]]);
        bf16x8 kl_ = ld8(&lkl[soF[ks][nt]]);
        sc[nt] = __builtin_amdgcn_mfma_f32_16x16x32_bf16(kh_, qfh[ks], sc[nt], 0, 0, 0);
        sc[nt] = __builtin_amdgcn_mfma_f32_16x16x32_bf16(kl_, qfh[ks], sc[nt], 0, 0, 0);
        sc[nt] = __builtin_amdgcn_mfma_f32_16x16x32_bf16(kh_, qfl[ks], sc[nt], 0, 0, 0);
      }
    }
    // ---- online softmax for qrow=l15: in-lane max over 16 keys + 2 shfl ----
    float mx = fmaxf(fmaxf(fmaxf(sc[0][0], sc[0][1]), fmaxf(sc[0][2], sc[0][3])),
                     fmaxf(fmaxf(sc[1][0], sc[1][1]), fmaxf(sc[1][2], sc[1][3])));
    float mx2 = fmaxf(fmaxf(fmaxf(sc[2][0], sc[2][1]), fmaxf(sc[2][2], sc[2][3])),
                      fmaxf(fmaxf(sc[3][0], sc[3][1]), fmaxf(sc[3][2], sc[3][3])));
    mx = fmaxf(mx, mx2);
    mx = fmaxf(mx, __shfl_xor(mx, 16));
    mx = fmaxf(mx, __shfl_xor(mx, 32));
    float mn = fmaxf(mi, mx);
    float alpha_s = ex2(mi - mn);
    mi = mn;
    // ---- P = exp2(sc - mn), packed ds_write_b64 into lp[qrow][key] ----
#pragma unroll
    for (int nt = 0; nt < 4; ++nt) {
      unsigned u01 = pk2(ex2(sc[nt][0] - mn), ex2(sc[nt][1] - mn));
      unsigned u23 = pk2(ex2(sc[nt][2] - mn), ex2(sc[nt][3] - mn));
      *(u32x2*)(&lpw[soP[nt]]) = u32x2{u01, u23};
    }
    // ---- broadcast alpha to O domain (qrow = quad*4+r) and rescale ----
    float av[4];
#pragma unroll
    for (int r = 0; r < 4; ++r) av[r] = __shfl(alpha_s, quad * 4 + r);
#pragma unroll
    for (int r = 0; r < 4; ++r) {
      lsum[r] *= av[r];
      o[0][r] *= av[r]; o[1][r] *= av[r]; o[2][r] *= av[r]; o[3][r] *= av[r];
    }
    // wave-private LDS write->read: drain DS queue (in-order per wave)
    asm volatile("s_waitcnt lgkmcnt(0)" ::: "memory");
    // ---- P @ V (+ ones-B MFMA accumulates the row-sum l) ----
    bf16x8 pa[2];
#pragma unroll
    for (int ks = 0; ks < 2; ++ks) pa[ks] = ld8(&lpw[soPa[ks]]);
    lsum = __builtin_amdgcn_mfma_f32_16x16x32_bf16(pa[0], onesf, lsum, 0, 0, 0);
    lsum = __builtin_amdgcn_mfma_f32_16x16x32_bf16(pa[1], onesf, lsum, 0, 0, 0);
#pragma unroll
    for (int nt = 0; nt < 4; ++nt)
#pragma unroll
      for (int ks = 0; ks < 2; ++ks) {
        bf16x8 bv = ld8(&lvt[soF[ks][nt]]);
        o[nt] = __builtin_amdgcn_mfma_f32_16x16x32_bf16(pa[ks], bv, o[nt], 0, 0, 0);
      }
  }
  // epilogue: out[b, s, h*64+d]
  float inv[4];
#pragma unroll
  for (int r = 0; r < 4; ++r) inv[r] = 1.0f / lsum[r];
#pragma unroll
  for (int nt = 0; nt < 4; ++nt)
#pragma unroll
    for (int r = 0; r < 4; ++r) {
      int srow = q0 + wave * 16 + quad * 4 + r;
      int d = nt * 16 + l15;
      out[(size_t)(b * 2048 + srow) * 1024 + h * 64 + d] = o[nt][r] * inv[r];
    }
}

extern "C" void kernel_launch(void* const* d_in, const int* in_sizes, int n_in,
                              void* d_out, int out_size, void* d_ws, size_t ws_size,
                              hipStream_t stream) {
  const float* q  = (const float*)d_in[0];
  const float* k  = (const float*)d_in[1];
  const float* v  = (const float*)d_in[2];
  const float* Wq = (const float*)d_in[3];
  const float* Wk = (const float*)d_in[4];
  const float* Wv = (const float*)d_in[5];
  u16* ws = (u16*)d_ws;
  float* out = (float*)d_out;

  convert_all<<<15360, 256, 0, stream>>>(q, k, v, Wq, Wk, Wv, ws);
  gemm_qkv<<<1536, 256, 0, stream>>>(ws);
  transpose_v<<<dim3(32, 32), 256, 0, stream>>>(ws + OFF_VH, ws + OFF_VT);
  attn<<<dim3(32, 16, 2), 256, 0, stream>>>(ws, out);
}